// Round 6
// baseline (1318.201 us; speedup 1.0000x reference)
//
#include <hip/hip_runtime.h>
#include <hip/hip_fp16.h>
#include <cstdint>
#include <cstddef>

// GCNII: h0 = relu(x@W_in + b_in); 8x { s = .9*Ahat@h + .1*h0; h = relu(s @ Wl) };
// out = h@W_out + b_out.  Ahat = D^-1/2 (A + I) D^-1/2 (deg over targets, +1 self loop).
// Activations fp16; weights transposed to fp16 once; MFMA f16 GEMMs (fp32 accum).
// CSR built via bucketed two-phase scatter (write-combining; plain scatter was 107MB
// WRITE_SIZE / 115us from per-edge 64B line dirtying).
// Aggregation standalone + LDS-free (latency-bound; needs max occupancy — round-4 lesson).

#define HID 128
#define BSHIFT 7   // 128 nodes per bucket

using f16x8 = __attribute__((ext_vector_type(8))) _Float16;
using f32x4 = __attribute__((ext_vector_type(4))) float;

// ---------------- preprocessing ----------------

__global__ void k_hist(const int* __restrict__ col, int E, int* __restrict__ cnt) {
  int e = blockIdx.x * blockDim.x + threadIdx.x;
  if (e < E) atomicAdd(&cnt[col[e]], 1);
}

// block reduce of cnt -> bsum, plus dinv = rsqrt(cnt+1)
__global__ __launch_bounds__(256) void k_blocksum_dinv(const int* __restrict__ cnt,
                                                       int* __restrict__ bsum,
                                                       float* __restrict__ dinv, int N) {
  __shared__ int s[256];
  int t = threadIdx.x;
  int i = blockIdx.x * 256 + t;
  int v = (i < N) ? cnt[i] : 0;
  if (i < N) dinv[i] = rsqrtf((float)v + 1.0f);  // +1 self loop
  s[t] = v;
  __syncthreads();
  for (int off = 128; off > 0; off >>= 1) {
    if (t < off) s[t] += s[t + off];
    __syncthreads();
  }
  if (t == 0) bsum[blockIdx.x] = s[0];
}

__global__ __launch_bounds__(512) void k_scan_bsum(const int* __restrict__ bsum,
                                                   int* __restrict__ bofs, int nb) {
  __shared__ int s[512];
  __shared__ int carry;
  int t = threadIdx.x;
  if (t == 0) carry = 0;
  __syncthreads();
  for (int base = 0; base < nb; base += 512) {
    int i = base + t;
    int v = (i < nb) ? bsum[i] : 0;
    s[t] = v;
    __syncthreads();
    for (int off = 1; off < 512; off <<= 1) {
      int a = (t >= off) ? s[t - off] : 0;
      __syncthreads();
      s[t] += a;
      __syncthreads();
    }
    if (i < nb) bofs[i] = carry + s[t] - v;
    __syncthreads();
    if (t == 0) carry += s[511];
    __syncthreads();
  }
}

__global__ __launch_bounds__(256) void k_scan_write(const int* __restrict__ cnt,
                                                    const int* __restrict__ bofs,
                                                    int* __restrict__ row_ptr, int N) {
  __shared__ int s[256];
  int t = threadIdx.x;
  int i = blockIdx.x * 256 + t;
  int v = (i < N) ? cnt[i] : 0;
  s[t] = v;
  __syncthreads();
  for (int off = 1; off < 256; off <<= 1) {
    int a = (t >= off) ? s[t - off] : 0;
    __syncthreads();
    s[t] += a;
    __syncthreads();
  }
  int excl = bofs[blockIdx.x] + s[t] - v;
  if (i < N) row_ptr[i] = excl;
  if (i == N - 1) row_ptr[N] = excl + v;
}

// phase A: scatter {src,dst} to bucket-major tmp (per-bucket frontier -> write-combines)
__global__ void k_scatterA(const int* __restrict__ row, const int* __restrict__ col,
                           int E, const int* __restrict__ row_ptr,
                           int* __restrict__ bfill, int2* __restrict__ tmp) {
  int e = blockIdx.x * blockDim.x + threadIdx.x;
  if (e >= E) return;
  int r = row[e], c = col[e];
  int b = c >> BSHIFT;
  int p = row_ptr[b << BSHIFT] + atomicAdd(&bfill[b], 1);
  tmp[p] = make_int2(r, c);
}

// phase B: within-bucket scatter to final CSR (output window L2-resident per bucket)
__global__ void k_scatterB(const int2* __restrict__ tmp, int E,
                           const int* __restrict__ row_ptr, int* __restrict__ fill,
                           int* __restrict__ csr_src) {
  int i = blockIdx.x * blockDim.x + threadIdx.x;
  if (i >= E) return;
  int2 t = tmp[i];
  int p = row_ptr[t.y] + atomicAdd(&fill[t.y], 1);
  csr_src[p] = t.x;
}

// one-shot: transpose+fp16-convert all weight matrices.
// Wt layout: [L x (128x128)] [W_in (128x128)] [W_out (64x128)]; each stored [n][k].
__global__ void k_wprep(const float* __restrict__ Wc, const float* __restrict__ W_in,
                        const float* __restrict__ W_out, _Float16* __restrict__ Wt,
                        int L) {
  int id = blockIdx.x * blockDim.x + threadIdx.x;
  int nl = L * 16384;
  if (id < nl) {
    int l = id >> 14, r = id & 16383;
    int k = r >> 7, n = r & 127;
    Wt[(size_t)l * 16384 + n * 128 + k] = (_Float16)Wc[(size_t)l * 16384 + k * 128 + n];
  } else if (id < nl + 16384) {
    int r = id - nl;
    int k = r >> 7, n = r & 127;
    Wt[(size_t)nl + n * 128 + k] = (_Float16)W_in[k * 128 + n];
  } else if (id < nl + 16384 + 8192) {
    int r = id - nl - 16384;
    int k = r >> 6, n = r & 63;
    Wt[(size_t)(nl + 16384) + n * 128 + k] = (_Float16)W_out[k * 64 + n];
  }
}

// ---------------- aggregation (one wave per node, fp16 gather, atomic/LDS-free) --------

__global__ __launch_bounds__(256) void k_aggregate16(
    const _Float16* __restrict__ hp, const _Float16* __restrict__ x0h,
    const float* __restrict__ dinv, const int* __restrict__ row_ptr,
    const int* __restrict__ csr_src, _Float16* __restrict__ support, int N) {
  const __half* h = (const __half*)hp;
  int node = blockIdx.x * 4 + (threadIdx.x >> 6);
  if (node >= N) return;
  int lane = threadIdx.x & 63;
  int beg = row_ptr[node], end = row_ptr[node + 1];
  float di = dinv[node];
  // acc = di*h[node] + sum dinv[s]*h[s];  support = .9*di*acc + .1*x0
  float2 f0 = __half22float2(((const __half2*)(h + (size_t)node * HID))[lane]);
  float ax = di * f0.x;
  float ay = di * f0.y;
  int j = beg;
  for (; j + 8 <= end; j += 8) {
    int s0 = csr_src[j],     s1 = csr_src[j + 1], s2 = csr_src[j + 2], s3 = csr_src[j + 3];
    int s4 = csr_src[j + 4], s5 = csr_src[j + 5], s6 = csr_src[j + 6], s7 = csr_src[j + 7];
    __half2 a0 = ((const __half2*)(h + (size_t)s0 * HID))[lane];
    __half2 a1 = ((const __half2*)(h + (size_t)s1 * HID))[lane];
    __half2 a2 = ((const __half2*)(h + (size_t)s2 * HID))[lane];
    __half2 a3 = ((const __half2*)(h + (size_t)s3 * HID))[lane];
    __half2 a4 = ((const __half2*)(h + (size_t)s4 * HID))[lane];
    __half2 a5 = ((const __half2*)(h + (size_t)s5 * HID))[lane];
    __half2 a6 = ((const __half2*)(h + (size_t)s6 * HID))[lane];
    __half2 a7 = ((const __half2*)(h + (size_t)s7 * HID))[lane];
    float w0 = dinv[s0], w1 = dinv[s1], w2 = dinv[s2], w3 = dinv[s3];
    float w4 = dinv[s4], w5 = dinv[s5], w6 = dinv[s6], w7 = dinv[s7];
    float2 f;
    f = __half22float2(a0); ax = fmaf(w0, f.x, ax); ay = fmaf(w0, f.y, ay);
    f = __half22float2(a1); ax = fmaf(w1, f.x, ax); ay = fmaf(w1, f.y, ay);
    f = __half22float2(a2); ax = fmaf(w2, f.x, ax); ay = fmaf(w2, f.y, ay);
    f = __half22float2(a3); ax = fmaf(w3, f.x, ax); ay = fmaf(w3, f.y, ay);
    f = __half22float2(a4); ax = fmaf(w4, f.x, ax); ay = fmaf(w4, f.y, ay);
    f = __half22float2(a5); ax = fmaf(w5, f.x, ax); ay = fmaf(w5, f.y, ay);
    f = __half22float2(a6); ax = fmaf(w6, f.x, ax); ay = fmaf(w6, f.y, ay);
    f = __half22float2(a7); ax = fmaf(w7, f.x, ax); ay = fmaf(w7, f.y, ay);
  }
  if (j + 4 <= end) {
    int s0 = csr_src[j], s1 = csr_src[j + 1], s2 = csr_src[j + 2], s3 = csr_src[j + 3];
    __half2 a0 = ((const __half2*)(h + (size_t)s0 * HID))[lane];
    __half2 a1 = ((const __half2*)(h + (size_t)s1 * HID))[lane];
    __half2 a2 = ((const __half2*)(h + (size_t)s2 * HID))[lane];
    __half2 a3 = ((const __half2*)(h + (size_t)s3 * HID))[lane];
    float w0 = dinv[s0], w1 = dinv[s1], w2 = dinv[s2], w3 = dinv[s3];
    float2 f;
    f = __half22float2(a0); ax = fmaf(w0, f.x, ax); ay = fmaf(w0, f.y, ay);
    f = __half22float2(a1); ax = fmaf(w1, f.x, ax); ay = fmaf(w1, f.y, ay);
    f = __half22float2(a2); ax = fmaf(w2, f.x, ax); ay = fmaf(w2, f.y, ay);
    f = __half22float2(a3); ax = fmaf(w3, f.x, ax); ay = fmaf(w3, f.y, ay);
    j += 4;
  }
  for (; j < end; ++j) {
    int s = csr_src[j];
    float w = dinv[s];
    float2 f = __half22float2(((const __half2*)(h + (size_t)s * HID))[lane]);
    ax = fmaf(w, f.x, ax);
    ay = fmaf(w, f.y, ay);
  }
  float2 xv = __half22float2(((const __half2*)((const __half*)x0h + (size_t)node * HID))[lane]);
  float s9 = 0.9f * di;
  float ox = s9 * ax + 0.1f * xv.x;
  float oy = s9 * ay + 0.1f * xv.y;
  ((__half2*)support)[(size_t)node * (HID / 2) + lane] = __floats2half2_rn(ox, oy);
}

// ---------------- MFMA GEMM: C[M][NC] = op(A[M][128] @ W),  Bt = W^T fp16 [NC][128] ----
// 256 threads = 4 waves; block tile 128 rows; wave: 32 rows = 2 m-tiles x NT n-tiles.
// A-frag: row=lane&15, k=(lane>>4)*8+i (16B/lane); B via Bt; C/D: col=lane&15,
// row=(lane>>4)*4+reg [m89].  AF32: A is fp32, converted in-register.

template <int NC, bool RELU, bool BIAS, bool AF32, bool OHALF>
__global__ __launch_bounds__(256) void k_mfma_gemm(const void* __restrict__ Av,
                                                   const _Float16* __restrict__ Bt,
                                                   const float* __restrict__ bias,
                                                   void* __restrict__ Cv, int M) {
  constexpr int NT = NC / 16;
  int tid = threadIdx.x;
  int w = tid >> 6, l = tid & 63;
  int lm = l & 15, kg = l >> 4;
  int row0 = blockIdx.x * 128 + w * 32;
  int r0 = min(row0 + lm, M - 1);        // clamp: values unused for r>=M (stores guarded)
  int r1 = min(row0 + 16 + lm, M - 1);

  f32x4 acc[2][NT];
#pragma unroll
  for (int mt = 0; mt < 2; ++mt)
#pragma unroll
    for (int nt = 0; nt < NT; ++nt) acc[mt][nt] = (f32x4){0.f, 0.f, 0.f, 0.f};

#pragma unroll
  for (int ks = 0; ks < 128; ks += 32) {
    f16x8 a0, a1;
    if (AF32) {
      const float* Af = (const float*)Av;
      float4 p0 = *(const float4*)(Af + (size_t)r0 * 128 + ks + kg * 8);
      float4 p1 = *(const float4*)(Af + (size_t)r0 * 128 + ks + kg * 8 + 4);
      float4 q0 = *(const float4*)(Af + (size_t)r1 * 128 + ks + kg * 8);
      float4 q1 = *(const float4*)(Af + (size_t)r1 * 128 + ks + kg * 8 + 4);
      a0[0] = (_Float16)p0.x; a0[1] = (_Float16)p0.y; a0[2] = (_Float16)p0.z; a0[3] = (_Float16)p0.w;
      a0[4] = (_Float16)p1.x; a0[5] = (_Float16)p1.y; a0[6] = (_Float16)p1.z; a0[7] = (_Float16)p1.w;
      a1[0] = (_Float16)q0.x; a1[1] = (_Float16)q0.y; a1[2] = (_Float16)q0.z; a1[3] = (_Float16)q0.w;
      a1[4] = (_Float16)q1.x; a1[5] = (_Float16)q1.y; a1[6] = (_Float16)q1.z; a1[7] = (_Float16)q1.w;
    } else {
      const _Float16* Ah = (const _Float16*)Av;
      a0 = *(const f16x8*)(Ah + (size_t)r0 * 128 + ks + kg * 8);
      a1 = *(const f16x8*)(Ah + (size_t)r1 * 128 + ks + kg * 8);
    }
#pragma unroll
    for (int nt = 0; nt < NT; ++nt) {
      f16x8 b = *(const f16x8*)(Bt + (size_t)(nt * 16 + lm) * 128 + ks + kg * 8);
      acc[0][nt] = __builtin_amdgcn_mfma_f32_16x16x32_f16(a0, b, acc[0][nt], 0, 0, 0);
      acc[1][nt] = __builtin_amdgcn_mfma_f32_16x16x32_f16(a1, b, acc[1][nt], 0, 0, 0);
    }
  }

#pragma unroll
  for (int mt = 0; mt < 2; ++mt) {
#pragma unroll
    for (int nt = 0; nt < NT; ++nt) {
      int colc = nt * 16 + lm;
      float bv = BIAS ? bias[colc] : 0.0f;
#pragma unroll
      for (int i = 0; i < 4; ++i) {
        int r = row0 + mt * 16 + kg * 4 + i;
        if (r >= M) continue;
        float v = acc[mt][nt][i] + bv;
        if (RELU) v = fmaxf(v, 0.0f);
        if (OHALF)
          ((_Float16*)Cv)[(size_t)r * NC + colc] = (_Float16)v;
        else
          ((float*)Cv)[(size_t)r * NC + colc] = v;
      }
    }
  }
}

// ---------------- launch ----------------

extern "C" void kernel_launch(void* const* d_in, const int* in_sizes, int n_in,
                              void* d_out, int out_size, void* d_ws, size_t ws_size,
                              hipStream_t stream) {
  const float* x     = (const float*)d_in[0];
  const int*   ei    = (const int*)d_in[1];
  const float* W_in  = (const float*)d_in[2];
  const float* b_in  = (const float*)d_in[3];
  const float* Wc    = (const float*)d_in[4];
  const float* W_out = (const float*)d_in[5];
  const float* b_out = (const float*)d_in[6];
  float* out = (float*)d_out;

  const int N = in_sizes[0] / HID;          // 100000
  const int E = in_sizes[1] / 2;            // 1600000
  const int L = in_sizes[4] / (HID * HID);  // 8
  const int nb = (N + 255) / 256;           // scan blocks
  const int nbk = (N + (1 << BSHIFT) - 1) >> BSHIFT;  // buckets
  const int* row = ei;       // sources
  const int* col = ei + E;   // targets

  char* p = (char*)d_ws;
  auto alloc = [&](size_t bytes) {
    char* q = p;
    p += (bytes + 255) & ~(size_t)255;
    return q;
  };
  _Float16* x0h   = (_Float16*)alloc((size_t)N * HID * 2);
  _Float16* sup16 = (_Float16*)alloc((size_t)N * HID * 2);
  _Float16* h16   = (_Float16*)alloc((size_t)N * HID * 2);
  _Float16* Wt    = (_Float16*)alloc((size_t)(L * 16384 + 16384 + 8192) * 2);
  int*    cnt     = (int*)alloc((size_t)N * 4);
  int*    row_ptr = (int*)alloc((size_t)(N + 1) * 4);
  int*    fill    = (int*)alloc((size_t)N * 4);
  int*    bfill   = (int*)alloc((size_t)nbk * 4);
  int*    bsum    = (int*)alloc((size_t)nb * 4);
  int*    bofs    = (int*)alloc((size_t)nb * 4);
  float*  dinv    = (float*)alloc((size_t)N * 4);
  int*    csr_src = (int*)alloc((size_t)E * 4);
  int2*   tmp     = (int2*)alloc((size_t)E * 8);
  (void)ws_size; (void)n_in; (void)out_size;

  const _Float16* Wt_in  = Wt + (size_t)L * 16384;
  const _Float16* Wt_out = Wt + (size_t)L * 16384 + 16384;

  hipMemsetAsync(cnt, 0, (size_t)N * 4, stream);
  hipMemsetAsync(fill, 0, (size_t)N * 4, stream);
  hipMemsetAsync(bfill, 0, (size_t)nbk * 4, stream);

  int nw = L * 16384 + 16384 + 8192;
  k_wprep<<<(nw + 255) / 256, 256, 0, stream>>>(Wc, W_in, W_out, Wt, L);
  k_hist<<<(E + 255) / 256, 256, 0, stream>>>(col, E, cnt);
  k_blocksum_dinv<<<nb, 256, 0, stream>>>(cnt, bsum, dinv, N);
  k_scan_bsum<<<1, 512, 0, stream>>>(bsum, bofs, nb);
  k_scan_write<<<nb, 256, 0, stream>>>(cnt, bofs, row_ptr, N);
  k_scatterA<<<(E + 255) / 256, 256, 0, stream>>>(row, col, E, row_ptr, bfill, tmp);
  k_scatterB<<<(E + 255) / 256, 256, 0, stream>>>(tmp, E, row_ptr, fill, csr_src);

  int ggrid = (N + 127) / 128;  // 782
  // input projection: fp32 x read directly, f16 convert in-register
  k_mfma_gemm<128, true, true, true, true><<<ggrid, 256, 0, stream>>>(x, Wt_in, b_in,
                                                                      x0h, N);

  const _Float16* hin = x0h;
  for (int l = 0; l < L; ++l) {
    k_aggregate16<<<(N + 3) / 4, 256, 0, stream>>>(hin, x0h, dinv, row_ptr, csr_src,
                                                   sup16, N);
    k_mfma_gemm<128, true, false, false, true><<<ggrid, 256, 0, stream>>>(
        sup16, Wt + (size_t)l * 16384, nullptr, h16, N);
    hin = h16;
  }
  // output projection (fp32 out)
  k_mfma_gemm<64, false, true, false, false><<<ggrid, 256, 0, stream>>>(hin, Wt_out,
                                                                        b_out, out, N);
}

// Round 7
// 990.235 us; speedup vs baseline: 1.3312x; 1.3312x over previous
//
#include <hip/hip_runtime.h>
#include <hip/hip_fp16.h>
#include <cstdint>
#include <cstddef>

// GCNII: h0 = relu(x@W_in + b_in); 8x { s = .9*Ahat@h + .1*h0; h = relu(s @ Wl) };
// out = h@W_out + b_out.  Ahat = D^-1/2 (A + I) D^-1/2 (deg over targets, +1 self loop).
// Activations fp16; weights transposed to fp16 once; MFMA f16 GEMMs (fp32 accum).
// CSR: plain per-node atomic scatter (round-6 bucketed scatter = atomic contention, 3x worse).
// Aggregation: 32 lanes/node, 2 nodes/wave, unroll 8 -> 16 row-gathers in flight/wave.
// Aggregation standalone + LDS-free (latency-bound; needs max occupancy — round-4 lesson).

#define HID 128

using f16x8 = __attribute__((ext_vector_type(8))) _Float16;
using f16x4 = __attribute__((ext_vector_type(4))) _Float16;
using f32x4 = __attribute__((ext_vector_type(4))) float;

// ---------------- preprocessing ----------------

__global__ void k_hist(const int* __restrict__ col, int E, int* __restrict__ cnt) {
  int e = blockIdx.x * blockDim.x + threadIdx.x;
  if (e < E) atomicAdd(&cnt[col[e]], 1);
}

// block reduce of cnt -> bsum, plus dinv = rsqrt(cnt+1)
__global__ __launch_bounds__(256) void k_blocksum_dinv(const int* __restrict__ cnt,
                                                       int* __restrict__ bsum,
                                                       float* __restrict__ dinv, int N) {
  __shared__ int s[256];
  int t = threadIdx.x;
  int i = blockIdx.x * 256 + t;
  int v = (i < N) ? cnt[i] : 0;
  if (i < N) dinv[i] = rsqrtf((float)v + 1.0f);  // +1 self loop
  s[t] = v;
  __syncthreads();
  for (int off = 128; off > 0; off >>= 1) {
    if (t < off) s[t] += s[t + off];
    __syncthreads();
  }
  if (t == 0) bsum[blockIdx.x] = s[0];
}

__global__ __launch_bounds__(512) void k_scan_bsum(const int* __restrict__ bsum,
                                                   int* __restrict__ bofs, int nb) {
  __shared__ int s[512];
  __shared__ int carry;
  int t = threadIdx.x;
  if (t == 0) carry = 0;
  __syncthreads();
  for (int base = 0; base < nb; base += 512) {
    int i = base + t;
    int v = (i < nb) ? bsum[i] : 0;
    s[t] = v;
    __syncthreads();
    for (int off = 1; off < 512; off <<= 1) {
      int a = (t >= off) ? s[t - off] : 0;
      __syncthreads();
      s[t] += a;
      __syncthreads();
    }
    if (i < nb) bofs[i] = carry + s[t] - v;
    __syncthreads();
    if (t == 0) carry += s[511];
    __syncthreads();
  }
}

__global__ __launch_bounds__(256) void k_scan_write(const int* __restrict__ cnt,
                                                    const int* __restrict__ bofs,
                                                    int* __restrict__ row_ptr, int N) {
  __shared__ int s[256];
  int t = threadIdx.x;
  int i = blockIdx.x * 256 + t;
  int v = (i < N) ? cnt[i] : 0;
  s[t] = v;
  __syncthreads();
  for (int off = 1; off < 256; off <<= 1) {
    int a = (t >= off) ? s[t - off] : 0;
    __syncthreads();
    s[t] += a;
    __syncthreads();
  }
  int excl = bofs[blockIdx.x] + s[t] - v;
  if (i < N) row_ptr[i] = excl;
  if (i == N - 1) row_ptr[N] = excl + v;
}

// scatter src into CSR; cnt used as countdown (destroyed) -> no separate fill array
__global__ void k_fill(const int* __restrict__ row, const int* __restrict__ col, int E,
                       const int* __restrict__ row_ptr, int* __restrict__ cnt,
                       int* __restrict__ csr_src) {
  int e = blockIdx.x * blockDim.x + threadIdx.x;
  if (e >= E) return;
  int r = row[e], c = col[e];
  int p = row_ptr[c] + atomicSub(&cnt[c], 1) - 1;
  csr_src[p] = r;
}

// one-shot: transpose+fp16-convert all weight matrices.
// Wt layout: [L x (128x128)] [W_in (128x128)] [W_out (64x128)]; each stored [n][k].
__global__ void k_wprep(const float* __restrict__ Wc, const float* __restrict__ W_in,
                        const float* __restrict__ W_out, _Float16* __restrict__ Wt,
                        int L) {
  int id = blockIdx.x * blockDim.x + threadIdx.x;
  int nl = L * 16384;
  if (id < nl) {
    int l = id >> 14, r = id & 16383;
    int k = r >> 7, n = r & 127;
    Wt[(size_t)l * 16384 + n * 128 + k] = (_Float16)Wc[(size_t)l * 16384 + k * 128 + n];
  } else if (id < nl + 16384) {
    int r = id - nl;
    int k = r >> 7, n = r & 127;
    Wt[(size_t)nl + n * 128 + k] = (_Float16)W_in[k * 128 + n];
  } else if (id < nl + 16384 + 8192) {
    int r = id - nl - 16384;
    int k = r >> 6, n = r & 63;
    Wt[(size_t)(nl + 16384) + n * 128 + k] = (_Float16)W_out[k * 64 + n];
  }
}

// ---------------- aggregation ----------------
// 32 lanes per node (lane owns dims [4*lane, 4*lane+4), one 8B f16x4 load per row),
// 2 nodes per wave, edge loop unroll 8 -> 16 independent row gathers in flight/wave.

__global__ __launch_bounds__(256) void k_aggregate16(
    const _Float16* __restrict__ h, const _Float16* __restrict__ x0h,
    const float* __restrict__ dinv, const int* __restrict__ row_ptr,
    const int* __restrict__ csr_src, _Float16* __restrict__ support, int N) {
  int node = blockIdx.x * 8 + (threadIdx.x >> 5);
  if (node >= N) return;
  int lane = threadIdx.x & 31;
  int d0 = lane * 4;
  int beg = row_ptr[node], end = row_ptr[node + 1];
  float di = dinv[node];

  // hoisted loads: self row + x0 slice (overlap with edge loop issue)
  f16x4 v0 = *(const f16x4*)(h + (size_t)node * HID + d0);
  f16x4 xv = *(const f16x4*)(x0h + (size_t)node * HID + d0);

  float a0 = di * (float)v0[0], a1 = di * (float)v0[1];
  float a2 = di * (float)v0[2], a3 = di * (float)v0[3];

  int j = beg;
  for (; j + 8 <= end; j += 8) {
    int s0 = csr_src[j],     s1 = csr_src[j + 1], s2 = csr_src[j + 2], s3 = csr_src[j + 3];
    int s4 = csr_src[j + 4], s5 = csr_src[j + 5], s6 = csr_src[j + 6], s7 = csr_src[j + 7];
    f16x4 r0 = *(const f16x4*)(h + (size_t)s0 * HID + d0);
    f16x4 r1 = *(const f16x4*)(h + (size_t)s1 * HID + d0);
    f16x4 r2 = *(const f16x4*)(h + (size_t)s2 * HID + d0);
    f16x4 r3 = *(const f16x4*)(h + (size_t)s3 * HID + d0);
    f16x4 r4 = *(const f16x4*)(h + (size_t)s4 * HID + d0);
    f16x4 r5 = *(const f16x4*)(h + (size_t)s5 * HID + d0);
    f16x4 r6 = *(const f16x4*)(h + (size_t)s6 * HID + d0);
    f16x4 r7 = *(const f16x4*)(h + (size_t)s7 * HID + d0);
    float w0 = dinv[s0], w1 = dinv[s1], w2 = dinv[s2], w3 = dinv[s3];
    float w4 = dinv[s4], w5 = dinv[s5], w6 = dinv[s6], w7 = dinv[s7];
    a0 = fmaf(w0, (float)r0[0], a0); a1 = fmaf(w0, (float)r0[1], a1);
    a2 = fmaf(w0, (float)r0[2], a2); a3 = fmaf(w0, (float)r0[3], a3);
    a0 = fmaf(w1, (float)r1[0], a0); a1 = fmaf(w1, (float)r1[1], a1);
    a2 = fmaf(w1, (float)r1[2], a2); a3 = fmaf(w1, (float)r1[3], a3);
    a0 = fmaf(w2, (float)r2[0], a0); a1 = fmaf(w2, (float)r2[1], a1);
    a2 = fmaf(w2, (float)r2[2], a2); a3 = fmaf(w2, (float)r2[3], a3);
    a0 = fmaf(w3, (float)r3[0], a0); a1 = fmaf(w3, (float)r3[1], a1);
    a2 = fmaf(w3, (float)r3[2], a2); a3 = fmaf(w3, (float)r3[3], a3);
    a0 = fmaf(w4, (float)r4[0], a0); a1 = fmaf(w4, (float)r4[1], a1);
    a2 = fmaf(w4, (float)r4[2], a2); a3 = fmaf(w4, (float)r4[3], a3);
    a0 = fmaf(w5, (float)r5[0], a0); a1 = fmaf(w5, (float)r5[1], a1);
    a2 = fmaf(w5, (float)r5[2], a2); a3 = fmaf(w5, (float)r5[3], a3);
    a0 = fmaf(w6, (float)r6[0], a0); a1 = fmaf(w6, (float)r6[1], a1);
    a2 = fmaf(w6, (float)r6[2], a2); a3 = fmaf(w6, (float)r6[3], a3);
    a0 = fmaf(w7, (float)r7[0], a0); a1 = fmaf(w7, (float)r7[1], a1);
    a2 = fmaf(w7, (float)r7[2], a2); a3 = fmaf(w7, (float)r7[3], a3);
  }
  if (j + 4 <= end) {
    int s0 = csr_src[j], s1 = csr_src[j + 1], s2 = csr_src[j + 2], s3 = csr_src[j + 3];
    f16x4 r0 = *(const f16x4*)(h + (size_t)s0 * HID + d0);
    f16x4 r1 = *(const f16x4*)(h + (size_t)s1 * HID + d0);
    f16x4 r2 = *(const f16x4*)(h + (size_t)s2 * HID + d0);
    f16x4 r3 = *(const f16x4*)(h + (size_t)s3 * HID + d0);
    float w0 = dinv[s0], w1 = dinv[s1], w2 = dinv[s2], w3 = dinv[s3];
    a0 = fmaf(w0, (float)r0[0], a0); a1 = fmaf(w0, (float)r0[1], a1);
    a2 = fmaf(w0, (float)r0[2], a2); a3 = fmaf(w0, (float)r0[3], a3);
    a0 = fmaf(w1, (float)r1[0], a0); a1 = fmaf(w1, (float)r1[1], a1);
    a2 = fmaf(w1, (float)r1[2], a2); a3 = fmaf(w1, (float)r1[3], a3);
    a0 = fmaf(w2, (float)r2[0], a0); a1 = fmaf(w2, (float)r2[1], a1);
    a2 = fmaf(w2, (float)r2[2], a2); a3 = fmaf(w2, (float)r2[3], a3);
    a0 = fmaf(w3, (float)r3[0], a0); a1 = fmaf(w3, (float)r3[1], a1);
    a2 = fmaf(w3, (float)r3[2], a2); a3 = fmaf(w3, (float)r3[3], a3);
    j += 4;
  }
  for (; j < end; ++j) {
    int s = csr_src[j];
    float w = dinv[s];
    f16x4 r = *(const f16x4*)(h + (size_t)s * HID + d0);
    a0 = fmaf(w, (float)r[0], a0); a1 = fmaf(w, (float)r[1], a1);
    a2 = fmaf(w, (float)r[2], a2); a3 = fmaf(w, (float)r[3], a3);
  }
  float s9 = 0.9f * di;
  f16x4 o;
  o[0] = (_Float16)(s9 * a0 + 0.1f * (float)xv[0]);
  o[1] = (_Float16)(s9 * a1 + 0.1f * (float)xv[1]);
  o[2] = (_Float16)(s9 * a2 + 0.1f * (float)xv[2]);
  o[3] = (_Float16)(s9 * a3 + 0.1f * (float)xv[3]);
  *(f16x4*)(support + (size_t)node * HID + d0) = o;
}

// ---------------- MFMA GEMM: C[M][NC] = op(A[M][128] @ W),  Bt = W^T fp16 [NC][128] ----
// 256 threads = 4 waves; block tile 128 rows; wave: 32 rows = 2 m-tiles x NT n-tiles.
// A-frag: row=lane&15, k=(lane>>4)*8+i (16B/lane); B via Bt; C/D: col=lane&15,
// row=(lane>>4)*4+reg [m89].  AF32: A is fp32, converted in-register.

template <int NC, bool RELU, bool BIAS, bool AF32, bool OHALF>
__global__ __launch_bounds__(256) void k_mfma_gemm(const void* __restrict__ Av,
                                                   const _Float16* __restrict__ Bt,
                                                   const float* __restrict__ bias,
                                                   void* __restrict__ Cv, int M) {
  constexpr int NT = NC / 16;
  int tid = threadIdx.x;
  int w = tid >> 6, l = tid & 63;
  int lm = l & 15, kg = l >> 4;
  int row0 = blockIdx.x * 128 + w * 32;
  int r0 = min(row0 + lm, M - 1);        // clamp: values unused for r>=M (stores guarded)
  int r1 = min(row0 + 16 + lm, M - 1);

  f32x4 acc[2][NT];
#pragma unroll
  for (int mt = 0; mt < 2; ++mt)
#pragma unroll
    for (int nt = 0; nt < NT; ++nt) acc[mt][nt] = (f32x4){0.f, 0.f, 0.f, 0.f};

#pragma unroll
  for (int ks = 0; ks < 128; ks += 32) {
    f16x8 a0, a1;
    if (AF32) {
      const float* Af = (const float*)Av;
      float4 p0 = *(const float4*)(Af + (size_t)r0 * 128 + ks + kg * 8);
      float4 p1 = *(const float4*)(Af + (size_t)r0 * 128 + ks + kg * 8 + 4);
      float4 q0 = *(const float4*)(Af + (size_t)r1 * 128 + ks + kg * 8);
      float4 q1 = *(const float4*)(Af + (size_t)r1 * 128 + ks + kg * 8 + 4);
      a0[0] = (_Float16)p0.x; a0[1] = (_Float16)p0.y; a0[2] = (_Float16)p0.z; a0[3] = (_Float16)p0.w;
      a0[4] = (_Float16)p1.x; a0[5] = (_Float16)p1.y; a0[6] = (_Float16)p1.z; a0[7] = (_Float16)p1.w;
      a1[0] = (_Float16)q0.x; a1[1] = (_Float16)q0.y; a1[2] = (_Float16)q0.z; a1[3] = (_Float16)q0.w;
      a1[4] = (_Float16)q1.x; a1[5] = (_Float16)q1.y; a1[6] = (_Float16)q1.z; a1[7] = (_Float16)q1.w;
    } else {
      const _Float16* Ah = (const _Float16*)Av;
      a0 = *(const f16x8*)(Ah + (size_t)r0 * 128 + ks + kg * 8);
      a1 = *(const f16x8*)(Ah + (size_t)r1 * 128 + ks + kg * 8);
    }
#pragma unroll
    for (int nt = 0; nt < NT; ++nt) {
      f16x8 b = *(const f16x8*)(Bt + (size_t)(nt * 16 + lm) * 128 + ks + kg * 8);
      acc[0][nt] = __builtin_amdgcn_mfma_f32_16x16x32_f16(a0, b, acc[0][nt], 0, 0, 0);
      acc[1][nt] = __builtin_amdgcn_mfma_f32_16x16x32_f16(a1, b, acc[1][nt], 0, 0, 0);
    }
  }

#pragma unroll
  for (int mt = 0; mt < 2; ++mt) {
#pragma unroll
    for (int nt = 0; nt < NT; ++nt) {
      int colc = nt * 16 + lm;
      float bv = BIAS ? bias[colc] : 0.0f;
#pragma unroll
      for (int i = 0; i < 4; ++i) {
        int r = row0 + mt * 16 + kg * 4 + i;
        if (r >= M) continue;
        float v = acc[mt][nt][i] + bv;
        if (RELU) v = fmaxf(v, 0.0f);
        if (OHALF)
          ((_Float16*)Cv)[(size_t)r * NC + colc] = (_Float16)v;
        else
          ((float*)Cv)[(size_t)r * NC + colc] = v;
      }
    }
  }
}

// ---------------- launch ----------------

extern "C" void kernel_launch(void* const* d_in, const int* in_sizes, int n_in,
                              void* d_out, int out_size, void* d_ws, size_t ws_size,
                              hipStream_t stream) {
  const float* x     = (const float*)d_in[0];
  const int*   ei    = (const int*)d_in[1];
  const float* W_in  = (const float*)d_in[2];
  const float* b_in  = (const float*)d_in[3];
  const float* Wc    = (const float*)d_in[4];
  const float* W_out = (const float*)d_in[5];
  const float* b_out = (const float*)d_in[6];
  float* out = (float*)d_out;

  const int N = in_sizes[0] / HID;          // 100000
  const int E = in_sizes[1] / 2;            // 1600000
  const int L = in_sizes[4] / (HID * HID);  // 8
  const int nb = (N + 255) / 256;           // scan blocks
  const int* row = ei;       // sources
  const int* col = ei + E;   // targets

  char* p = (char*)d_ws;
  auto alloc = [&](size_t bytes) {
    char* q = p;
    p += (bytes + 255) & ~(size_t)255;
    return q;
  };
  _Float16* x0h   = (_Float16*)alloc((size_t)N * HID * 2);
  _Float16* sup16 = (_Float16*)alloc((size_t)N * HID * 2);
  _Float16* h16   = (_Float16*)alloc((size_t)N * HID * 2);
  _Float16* Wt    = (_Float16*)alloc((size_t)(L * 16384 + 16384 + 8192) * 2);
  int*    cnt     = (int*)alloc((size_t)N * 4);
  int*    row_ptr = (int*)alloc((size_t)(N + 1) * 4);
  int*    bsum    = (int*)alloc((size_t)nb * 4);
  int*    bofs    = (int*)alloc((size_t)nb * 4);
  float*  dinv    = (float*)alloc((size_t)N * 4);
  int*    csr_src = (int*)alloc((size_t)E * 4);
  (void)ws_size; (void)n_in; (void)out_size;

  const _Float16* Wt_in  = Wt + (size_t)L * 16384;
  const _Float16* Wt_out = Wt + (size_t)L * 16384 + 16384;

  hipMemsetAsync(cnt, 0, (size_t)N * 4, stream);

  int nw = L * 16384 + 16384 + 8192;
  k_wprep<<<(nw + 255) / 256, 256, 0, stream>>>(Wc, W_in, W_out, Wt, L);
  k_hist<<<(E + 255) / 256, 256, 0, stream>>>(col, E, cnt);
  k_blocksum_dinv<<<nb, 256, 0, stream>>>(cnt, bsum, dinv, N);
  k_scan_bsum<<<1, 512, 0, stream>>>(bsum, bofs, nb);
  k_scan_write<<<nb, 256, 0, stream>>>(cnt, bofs, row_ptr, N);
  // k_fill consumes cnt as a countdown (cnt is dead afterwards)
  k_fill<<<(E + 255) / 256, 256, 0, stream>>>(row, col, E, row_ptr, cnt, csr_src);

  int ggrid = (N + 127) / 128;  // 782
  // input projection: fp32 x read directly, f16 convert in-register
  k_mfma_gemm<128, true, true, true, true><<<ggrid, 256, 0, stream>>>(x, Wt_in, b_in,
                                                                      x0h, N);

  const _Float16* hin = x0h;
  int agrid = (N + 7) / 8;  // 12500
  for (int l = 0; l < L; ++l) {
    k_aggregate16<<<agrid, 256, 0, stream>>>(hin, x0h, dinv, row_ptr, csr_src,
                                             sup16, N);
    k_mfma_gemm<128, true, false, false, true><<<ggrid, 256, 0, stream>>>(
        sup16, Wt + (size_t)l * 16384, nullptr, h16, N);
    hin = h16;
  }
  // output projection (fp32 out)
  k_mfma_gemm<64, false, true, false, false><<<ggrid, 256, 0, stream>>>(hin, Wt_out,
                                                                        b_out, out, N);
}

// Round 8
// 856.540 us; speedup vs baseline: 1.5390x; 1.1561x over previous
//
#include <hip/hip_runtime.h>
#include <hip/hip_fp16.h>
#include <cstdint>
#include <cstddef>

// GCNII: h0 = relu(x@W_in + b_in); 8x { s = .9*Ahat@h + .1*h0; h = relu(s @ Wl) };
// out = h@W_out + b_out.  Ahat = D^-1/2 (A + I) D^-1/2 (deg over targets, +1 self loop).
// Activations fp16; weights transposed to fp16 once; MFMA f16 GEMMs (fp32 accum).
// CSR build: LDS-privatized radix partition (bucket = dst>>9, R=196).
//   - plain per-edge scatter costs 64B HBM write-granule per 4B store (107MB, 122us, r3/r7)
//   - global per-bucket frontier atomics serialize (782 ctrs x 2050 = 376us, r6)
//   - so: LDS hist -> one range-reservation atomic per (block,bucket) -> LDS frontier ->
//     contiguous ~21-int runs that merge in L2; partB scatters within an LDS slice and
//     streams it out coalesced, emitting row_ptr + dinv for free (kills hist+scan chain).
// Aggregation: 32 lanes/node, 2 nodes/wave, unroll 8, LDS-free (latency-bound; r4 lesson).

#define HID 128
#define BKSH 9                 // bucket = dst >> 9  (512 nodes per bucket)
#define RMAX 256               // LDS array bound (R = ceil(N/512) = 196 for N=100k)
#define SLICE_CAP 11264        // partB LDS slice entries (E/R ~ 8163, +30% headroom)

using f16x8 = __attribute__((ext_vector_type(8))) _Float16;
using f16x4 = __attribute__((ext_vector_type(4))) _Float16;
using f32x4 = __attribute__((ext_vector_type(4))) float;

// ---------------- CSR build: radix partition ----------------

// per-block LDS histogram of edge buckets, flushed once per (block, bucket)
__global__ __launch_bounds__(512) void k_bhist(const int* __restrict__ col, int E,
                                               int* __restrict__ bcnt, int R) {
  __shared__ int lh[RMAX];
  int tid = threadIdx.x;
  if (tid < R) lh[tid] = 0;
  __syncthreads();
  int base = blockIdx.x * 4096;
#pragma unroll
  for (int i = 0; i < 8; ++i) {
    int e = base + i * 512 + tid;
    if (e < E) atomicAdd(&lh[col[e] >> BKSH], 1);
  }
  __syncthreads();
  if (tid < R && lh[tid]) atomicAdd(&bcnt[tid], lh[tid]);
}

// scan R bucket counts -> gb[0..R] (gb[R]=E), init gfront=gb
__global__ __launch_bounds__(256) void k_scan196(const int* __restrict__ bcnt,
                                                 int* __restrict__ gb,
                                                 int* __restrict__ gfront, int R) {
  __shared__ int s[256];
  int t = threadIdx.x;
  int v = (t < R) ? bcnt[t] : 0;
  s[t] = v;
  __syncthreads();
  for (int off = 1; off < 256; off <<= 1) {
    int a = (t >= off) ? s[t - off] : 0;
    __syncthreads();
    s[t] += a;
    __syncthreads();
  }
  int excl = s[t] - v;
  if (t < R) {
    gb[t] = excl;
    gfront[t] = excl;
  }
  if (t == 255) gb[R] = s[255];
}

// partition {src,dst} into bucket-major tmp, packed (src<<9)|dstlow
__global__ __launch_bounds__(512) void k_partA(const int* __restrict__ row,
                                               const int* __restrict__ col, int E,
                                               int* __restrict__ gfront,
                                               int* __restrict__ tmp, int R) {
  __shared__ int lh[RMAX], base[RMAX], fr[RMAX];
  int tid = threadIdx.x;
  if (tid < R) { lh[tid] = 0; fr[tid] = 0; }
  __syncthreads();
  int b0 = blockIdx.x * 4096;
  int r[8], c[8], bk[8];
  bool ok[8];
#pragma unroll
  for (int i = 0; i < 8; ++i) {
    int e = b0 + i * 512 + tid;
    ok[i] = e < E;
    if (ok[i]) {
      r[i] = row[e];
      c[i] = col[e];
      bk[i] = c[i] >> BKSH;
      atomicAdd(&lh[bk[i]], 1);
    }
  }
  __syncthreads();
  if (tid < R && lh[tid] > 0) base[tid] = atomicAdd(&gfront[tid], lh[tid]);
  __syncthreads();
#pragma unroll
  for (int i = 0; i < 8; ++i) {
    if (ok[i]) {
      int o = atomicAdd(&fr[bk[i]], 1);
      tmp[base[bk[i]] + o] = (r[i] << BKSH) | (c[i] & ((1 << BKSH) - 1));
    }
  }
}

// per-bucket: LDS counting sort -> csr_src (coalesced writeout), row_ptr, dinv
__global__ __launch_bounds__(512) void k_partB(const int* __restrict__ tmp,
                                               const int* __restrict__ gb,
                                               int* __restrict__ csr_src,
                                               int* __restrict__ row_ptr,
                                               float* __restrict__ dinv, int N, int E,
                                               int R) {
  __shared__ int h2[512], pref[512];
  __shared__ int slice[SLICE_CAP];
  int tid = threadIdx.x;
  int b = blockIdx.x;
  int lo = gb[b], hi = gb[b + 1];
  int cnt = hi - lo;
  h2[tid] = 0;
  __syncthreads();
  for (int k = tid; k < cnt; k += 512) atomicAdd(&h2[tmp[lo + k] & 511], 1);
  __syncthreads();
  int v = h2[tid];
  pref[tid] = v;
  __syncthreads();
  for (int off = 1; off < 512; off <<= 1) {
    int a = (tid >= off) ? pref[tid - off] : 0;
    __syncthreads();
    pref[tid] += a;
    __syncthreads();
  }
  int excl = pref[tid] - v;
  int node = b * 512 + tid;
  if (node < N) {
    row_ptr[node] = lo + excl;
    dinv[node] = rsqrtf((float)v + 1.0f);  // +1 self loop
  }
  if (b == R - 1 && tid == 0) row_ptr[N] = E;
  __syncthreads();
  pref[tid] = excl;   // store exclusive prefix for placement
  h2[tid] = 0;        // frontier
  __syncthreads();
  for (int k = tid; k < cnt; k += 512) {
    int ent = tmp[lo + k];
    int nd = ent & 511;
    int o = pref[nd] + atomicAdd(&h2[nd], 1);
    if (o < SLICE_CAP) slice[o] = ent >> BKSH;
    else csr_src[lo + o] = ent >> BKSH;  // overflow fallback (never for this data)
  }
  __syncthreads();
  int lim = cnt < SLICE_CAP ? cnt : SLICE_CAP;
  for (int k = tid; k < lim; k += 512) csr_src[lo + k] = slice[k];
}

// ---------------- weight prep: transpose+fp16 all weights ----------------
// Wt layout: [L x (128x128)] [W_in (128x128)] [W_out (64x128)]; each stored [n][k].
__global__ void k_wprep(const float* __restrict__ Wc, const float* __restrict__ W_in,
                        const float* __restrict__ W_out, _Float16* __restrict__ Wt,
                        int L) {
  int id = blockIdx.x * blockDim.x + threadIdx.x;
  int nl = L * 16384;
  if (id < nl) {
    int l = id >> 14, r = id & 16383;
    int k = r >> 7, n = r & 127;
    Wt[(size_t)l * 16384 + n * 128 + k] = (_Float16)Wc[(size_t)l * 16384 + k * 128 + n];
  } else if (id < nl + 16384) {
    int r = id - nl;
    int k = r >> 7, n = r & 127;
    Wt[(size_t)nl + n * 128 + k] = (_Float16)W_in[k * 128 + n];
  } else if (id < nl + 16384 + 8192) {
    int r = id - nl - 16384;
    int k = r >> 6, n = r & 63;
    Wt[(size_t)(nl + 16384) + n * 128 + k] = (_Float16)W_out[k * 64 + n];
  }
}

// ---------------- aggregation ----------------
// 32 lanes per node (lane owns dims [4*lane, 4*lane+4), one 8B f16x4 load per row),
// 2 nodes per wave, edge loop unroll 8 -> 16 independent row gathers in flight/wave.

__global__ __launch_bounds__(256) void k_aggregate16(
    const _Float16* __restrict__ h, const _Float16* __restrict__ x0h,
    const float* __restrict__ dinv, const int* __restrict__ row_ptr,
    const int* __restrict__ csr_src, _Float16* __restrict__ support, int N) {
  int node = blockIdx.x * 8 + (threadIdx.x >> 5);
  if (node >= N) return;
  int lane = threadIdx.x & 31;
  int d0 = lane * 4;
  int beg = row_ptr[node], end = row_ptr[node + 1];
  float di = dinv[node];

  f16x4 v0 = *(const f16x4*)(h + (size_t)node * HID + d0);
  f16x4 xv = *(const f16x4*)(x0h + (size_t)node * HID + d0);

  float a0 = di * (float)v0[0], a1 = di * (float)v0[1];
  float a2 = di * (float)v0[2], a3 = di * (float)v0[3];

  int j = beg;
  for (; j + 8 <= end; j += 8) {
    int s0 = csr_src[j],     s1 = csr_src[j + 1], s2 = csr_src[j + 2], s3 = csr_src[j + 3];
    int s4 = csr_src[j + 4], s5 = csr_src[j + 5], s6 = csr_src[j + 6], s7 = csr_src[j + 7];
    f16x4 r0 = *(const f16x4*)(h + (size_t)s0 * HID + d0);
    f16x4 r1 = *(const f16x4*)(h + (size_t)s1 * HID + d0);
    f16x4 r2 = *(const f16x4*)(h + (size_t)s2 * HID + d0);
    f16x4 r3 = *(const f16x4*)(h + (size_t)s3 * HID + d0);
    f16x4 r4 = *(const f16x4*)(h + (size_t)s4 * HID + d0);
    f16x4 r5 = *(const f16x4*)(h + (size_t)s5 * HID + d0);
    f16x4 r6 = *(const f16x4*)(h + (size_t)s6 * HID + d0);
    f16x4 r7 = *(const f16x4*)(h + (size_t)s7 * HID + d0);
    float w0 = dinv[s0], w1 = dinv[s1], w2 = dinv[s2], w3 = dinv[s3];
    float w4 = dinv[s4], w5 = dinv[s5], w6 = dinv[s6], w7 = dinv[s7];
    a0 = fmaf(w0, (float)r0[0], a0); a1 = fmaf(w0, (float)r0[1], a1);
    a2 = fmaf(w0, (float)r0[2], a2); a3 = fmaf(w0, (float)r0[3], a3);
    a0 = fmaf(w1, (float)r1[0], a0); a1 = fmaf(w1, (float)r1[1], a1);
    a2 = fmaf(w1, (float)r1[2], a2); a3 = fmaf(w1, (float)r1[3], a3);
    a0 = fmaf(w2, (float)r2[0], a0); a1 = fmaf(w2, (float)r2[1], a1);
    a2 = fmaf(w2, (float)r2[2], a2); a3 = fmaf(w2, (float)r2[3], a3);
    a0 = fmaf(w3, (float)r3[0], a0); a1 = fmaf(w3, (float)r3[1], a1);
    a2 = fmaf(w3, (float)r3[2], a2); a3 = fmaf(w3, (float)r3[3], a3);
    a0 = fmaf(w4, (float)r4[0], a0); a1 = fmaf(w4, (float)r4[1], a1);
    a2 = fmaf(w4, (float)r4[2], a2); a3 = fmaf(w4, (float)r4[3], a3);
    a0 = fmaf(w5, (float)r5[0], a0); a1 = fmaf(w5, (float)r5[1], a1);
    a2 = fmaf(w5, (float)r5[2], a2); a3 = fmaf(w5, (float)r5[3], a3);
    a0 = fmaf(w6, (float)r6[0], a0); a1 = fmaf(w6, (float)r6[1], a1);
    a2 = fmaf(w6, (float)r6[2], a2); a3 = fmaf(w6, (float)r6[3], a3);
    a0 = fmaf(w7, (float)r7[0], a0); a1 = fmaf(w7, (float)r7[1], a1);
    a2 = fmaf(w7, (float)r7[2], a2); a3 = fmaf(w7, (float)r7[3], a3);
  }
  if (j + 4 <= end) {
    int s0 = csr_src[j], s1 = csr_src[j + 1], s2 = csr_src[j + 2], s3 = csr_src[j + 3];
    f16x4 r0 = *(const f16x4*)(h + (size_t)s0 * HID + d0);
    f16x4 r1 = *(const f16x4*)(h + (size_t)s1 * HID + d0);
    f16x4 r2 = *(const f16x4*)(h + (size_t)s2 * HID + d0);
    f16x4 r3 = *(const f16x4*)(h + (size_t)s3 * HID + d0);
    float w0 = dinv[s0], w1 = dinv[s1], w2 = dinv[s2], w3 = dinv[s3];
    a0 = fmaf(w0, (float)r0[0], a0); a1 = fmaf(w0, (float)r0[1], a1);
    a2 = fmaf(w0, (float)r0[2], a2); a3 = fmaf(w0, (float)r0[3], a3);
    a0 = fmaf(w1, (float)r1[0], a0); a1 = fmaf(w1, (float)r1[1], a1);
    a2 = fmaf(w1, (float)r1[2], a2); a3 = fmaf(w1, (float)r1[3], a3);
    a0 = fmaf(w2, (float)r2[0], a0); a1 = fmaf(w2, (float)r2[1], a1);
    a2 = fmaf(w2, (float)r2[2], a2); a3 = fmaf(w2, (float)r2[3], a3);
    a0 = fmaf(w3, (float)r3[0], a0); a1 = fmaf(w3, (float)r3[1], a1);
    a2 = fmaf(w3, (float)r3[2], a2); a3 = fmaf(w3, (float)r3[3], a3);
    j += 4;
  }
  for (; j < end; ++j) {
    int s = csr_src[j];
    float w = dinv[s];
    f16x4 r = *(const f16x4*)(h + (size_t)s * HID + d0);
    a0 = fmaf(w, (float)r[0], a0); a1 = fmaf(w, (float)r[1], a1);
    a2 = fmaf(w, (float)r[2], a2); a3 = fmaf(w, (float)r[3], a3);
  }
  float s9 = 0.9f * di;
  f16x4 o;
  o[0] = (_Float16)(s9 * a0 + 0.1f * (float)xv[0]);
  o[1] = (_Float16)(s9 * a1 + 0.1f * (float)xv[1]);
  o[2] = (_Float16)(s9 * a2 + 0.1f * (float)xv[2]);
  o[3] = (_Float16)(s9 * a3 + 0.1f * (float)xv[3]);
  *(f16x4*)(support + (size_t)node * HID + d0) = o;
}

// ---------------- MFMA GEMM: C[M][NC] = op(A[M][128] @ W),  Bt = W^T fp16 [NC][128] ----
// 256 threads = 4 waves; block tile 128 rows; wave: 32 rows = 2 m-tiles x NT n-tiles.
// A-frag: row=lane&15, k=(lane>>4)*8+i (16B/lane); B via Bt; C/D: col=lane&15,
// row=(lane>>4)*4+reg [m89].  AF32: A is fp32, converted in-register.

template <int NC, bool RELU, bool BIAS, bool AF32, bool OHALF>
__global__ __launch_bounds__(256) void k_mfma_gemm(const void* __restrict__ Av,
                                                   const _Float16* __restrict__ Bt,
                                                   const float* __restrict__ bias,
                                                   void* __restrict__ Cv, int M) {
  constexpr int NT = NC / 16;
  int tid = threadIdx.x;
  int w = tid >> 6, l = tid & 63;
  int lm = l & 15, kg = l >> 4;
  int row0 = blockIdx.x * 128 + w * 32;
  int r0 = min(row0 + lm, M - 1);        // clamp: values unused for r>=M (stores guarded)
  int r1 = min(row0 + 16 + lm, M - 1);

  f32x4 acc[2][NT];
#pragma unroll
  for (int mt = 0; mt < 2; ++mt)
#pragma unroll
    for (int nt = 0; nt < NT; ++nt) acc[mt][nt] = (f32x4){0.f, 0.f, 0.f, 0.f};

#pragma unroll
  for (int ks = 0; ks < 128; ks += 32) {
    f16x8 a0, a1;
    if (AF32) {
      const float* Af = (const float*)Av;
      float4 p0 = *(const float4*)(Af + (size_t)r0 * 128 + ks + kg * 8);
      float4 p1 = *(const float4*)(Af + (size_t)r0 * 128 + ks + kg * 8 + 4);
      float4 q0 = *(const float4*)(Af + (size_t)r1 * 128 + ks + kg * 8);
      float4 q1 = *(const float4*)(Af + (size_t)r1 * 128 + ks + kg * 8 + 4);
      a0[0] = (_Float16)p0.x; a0[1] = (_Float16)p0.y; a0[2] = (_Float16)p0.z; a0[3] = (_Float16)p0.w;
      a0[4] = (_Float16)p1.x; a0[5] = (_Float16)p1.y; a0[6] = (_Float16)p1.z; a0[7] = (_Float16)p1.w;
      a1[0] = (_Float16)q0.x; a1[1] = (_Float16)q0.y; a1[2] = (_Float16)q0.z; a1[3] = (_Float16)q0.w;
      a1[4] = (_Float16)q1.x; a1[5] = (_Float16)q1.y; a1[6] = (_Float16)q1.z; a1[7] = (_Float16)q1.w;
    } else {
      const _Float16* Ah = (const _Float16*)Av;
      a0 = *(const f16x8*)(Ah + (size_t)r0 * 128 + ks + kg * 8);
      a1 = *(const f16x8*)(Ah + (size_t)r1 * 128 + ks + kg * 8);
    }
#pragma unroll
    for (int nt = 0; nt < NT; ++nt) {
      f16x8 b = *(const f16x8*)(Bt + (size_t)(nt * 16 + lm) * 128 + ks + kg * 8);
      acc[0][nt] = __builtin_amdgcn_mfma_f32_16x16x32_f16(a0, b, acc[0][nt], 0, 0, 0);
      acc[1][nt] = __builtin_amdgcn_mfma_f32_16x16x32_f16(a1, b, acc[1][nt], 0, 0, 0);
    }
  }

#pragma unroll
  for (int mt = 0; mt < 2; ++mt) {
#pragma unroll
    for (int nt = 0; nt < NT; ++nt) {
      int colc = nt * 16 + lm;
      float bv = BIAS ? bias[colc] : 0.0f;
#pragma unroll
      for (int i = 0; i < 4; ++i) {
        int r = row0 + mt * 16 + kg * 4 + i;
        if (r >= M) continue;
        float v = acc[mt][nt][i] + bv;
        if (RELU) v = fmaxf(v, 0.0f);
        if (OHALF)
          ((_Float16*)Cv)[(size_t)r * NC + colc] = (_Float16)v;
        else
          ((float*)Cv)[(size_t)r * NC + colc] = v;
      }
    }
  }
}

// ---------------- launch ----------------

extern "C" void kernel_launch(void* const* d_in, const int* in_sizes, int n_in,
                              void* d_out, int out_size, void* d_ws, size_t ws_size,
                              hipStream_t stream) {
  const float* x     = (const float*)d_in[0];
  const int*   ei    = (const int*)d_in[1];
  const float* W_in  = (const float*)d_in[2];
  const float* b_in  = (const float*)d_in[3];
  const float* Wc    = (const float*)d_in[4];
  const float* W_out = (const float*)d_in[5];
  const float* b_out = (const float*)d_in[6];
  float* out = (float*)d_out;

  const int N = in_sizes[0] / HID;          // 100000
  const int E = in_sizes[1] / 2;            // 1600000
  const int L = in_sizes[4] / (HID * HID);  // 8
  const int R = (N + 511) >> BKSH;          // 196 buckets
  const int* row = ei;       // sources
  const int* col = ei + E;   // targets

  char* p = (char*)d_ws;
  auto alloc = [&](size_t bytes) {
    char* q = p;
    p += (bytes + 255) & ~(size_t)255;
    return q;
  };
  _Float16* x0h   = (_Float16*)alloc((size_t)N * HID * 2);
  _Float16* sup16 = (_Float16*)alloc((size_t)N * HID * 2);
  _Float16* h16   = (_Float16*)alloc((size_t)N * HID * 2);
  _Float16* Wt    = (_Float16*)alloc((size_t)(L * 16384 + 16384 + 8192) * 2);
  int*    row_ptr = (int*)alloc((size_t)(N + 1) * 4);
  float*  dinv    = (float*)alloc((size_t)N * 4);
  int*    csr_src = (int*)alloc((size_t)E * 4);
  int*    tmp     = (int*)alloc((size_t)E * 4);
  int*    bcnt    = (int*)alloc((size_t)R * 4);
  int*    gb      = (int*)alloc((size_t)(R + 1) * 4);
  int*    gfront  = (int*)alloc((size_t)R * 4);
  (void)ws_size; (void)n_in; (void)out_size;

  const _Float16* Wt_in  = Wt + (size_t)L * 16384;
  const _Float16* Wt_out = Wt + (size_t)L * 16384 + 16384;

  hipMemsetAsync(bcnt, 0, (size_t)R * 4, stream);

  int nw = L * 16384 + 16384 + 8192;
  int nbe = (E + 4095) / 4096;  // 391
  k_wprep<<<(nw + 255) / 256, 256, 0, stream>>>(Wc, W_in, W_out, Wt, L);
  k_bhist<<<nbe, 512, 0, stream>>>(col, E, bcnt, R);
  k_scan196<<<1, 256, 0, stream>>>(bcnt, gb, gfront, R);
  k_partA<<<nbe, 512, 0, stream>>>(row, col, E, gfront, tmp, R);
  k_partB<<<R, 512, 0, stream>>>(tmp, gb, csr_src, row_ptr, dinv, N, E, R);

  int ggrid = (N + 127) / 128;  // 782
  // input projection: fp32 x read directly, f16 convert in-register
  k_mfma_gemm<128, true, true, true, true><<<ggrid, 256, 0, stream>>>(x, Wt_in, b_in,
                                                                      x0h, N);

  const _Float16* hin = x0h;
  int agrid = (N + 7) / 8;  // 12500
  for (int l = 0; l < L; ++l) {
    k_aggregate16<<<agrid, 256, 0, stream>>>(hin, x0h, dinv, row_ptr, csr_src,
                                             sup16, N);
    k_mfma_gemm<128, true, false, false, true><<<ggrid, 256, 0, stream>>>(
        sup16, Wt + (size_t)l * 16384, nullptr, h16, N);
    hin = h16;
  }
  // output projection (fp32 out)
  k_mfma_gemm<64, false, true, false, false><<<ggrid, 256, 0, stream>>>(hin, Wt_out,
                                                                        b_out, out, N);
}